// Round 3
// baseline (282.805 us; speedup 1.0000x reference)
//
#include <hip/hip_runtime.h>

#define NN 1024
#define CH ((size_t)NN * (size_t)NN)

// ---- float4 elementwise helpers ----
__device__ __forceinline__ float4 v_add(float4 a, float4 b) {
    return make_float4(a.x + b.x, a.y + b.y, a.z + b.z, a.w + b.w);
}
__device__ __forceinline__ float4 v_sub(float4 a, float4 b) {
    return make_float4(a.x - b.x, a.y - b.y, a.z - b.z, a.w - b.w);
}
__device__ __forceinline__ float4 v_mul(float4 a, float4 b) {
    return make_float4(a.x * b.x, a.y * b.y, a.z * b.z, a.w * b.w);
}
__device__ __forceinline__ float4 v_fma(float4 a, float4 b, float4 c) {
    return make_float4(fmaf(a.x, b.x, c.x), fmaf(a.y, b.y, c.y),
                       fmaf(a.z, b.z, c.z), fmaf(a.w, b.w, c.w));
}
__device__ __forceinline__ float4 v_fmas(float s, float4 a, float4 c) {
    return make_float4(fmaf(s, a.x, c.x), fmaf(s, a.y, c.y),
                       fmaf(s, a.z, c.z), fmaf(s, a.w, c.w));
}
__device__ __forceinline__ float4 v_scale(float s, float4 a) {
    return make_float4(s * a.x, s * a.y, s * a.z, s * a.w);
}

__device__ __forceinline__ float4 ldf4(const float* p) { return *(const float4*)p; }

__device__ __forceinline__ int clampr(int r) { return r < 0 ? 0 : (r > NN - 1 ? NN - 1 : r); }

// x-derivatives for 4 pixels at x = 4*tx .. 4*tx+3; l/c/r = left/center/right float4.
__device__ __forceinline__ void xder(float4 l, float4 c, float4 r, int tx,
                                     float4& d1, float4& d2) {
    d1.x = 0.5f * (c.y - l.w);
    d1.y = 0.5f * (c.z - c.x);
    d1.z = 0.5f * (c.w - c.y);
    d1.w = 0.5f * (r.x - c.z);
    d2.x = 0.25f * (c.z - 2.0f * c.x + l.z);
    d2.y = 0.25f * (c.w - 2.0f * c.y + l.w);
    d2.z = 0.25f * (r.x - 2.0f * c.z + c.x);
    d2.w = 0.25f * (r.y - 2.0f * c.w + c.y);
    if (tx == 0) {                  // pixels i=0, i=1
        d1.x = c.y - c.x;
        d2.x = 0.5f * c.z - c.y + 0.5f * c.x;
        d2.y = 0.25f * c.w - 0.75f * c.y + 0.5f * c.x;
    } else if (tx == NN / 4 - 1) {  // pixels i=n-2, i=n-1
        d2.z = 0.25f * c.x - 0.75f * c.z + 0.5f * c.w;
        d1.w = c.w - c.z;
        d2.w = 0.5f * c.y - c.z + 0.5f * c.w;
    }
}

__device__ __forceinline__ void xder1(float4 l, float4 c, float4 r, int tx, float4& d1) {
    d1.x = 0.5f * (c.y - l.w);
    d1.y = 0.5f * (c.z - c.x);
    d1.z = 0.5f * (c.w - c.y);
    d1.w = 0.5f * (r.x - c.z);
    if (tx == 0)               d1.x = c.y - c.x;
    else if (tx == NN / 4 - 1) d1.w = c.w - c.z;
}

// y-derivatives from rows y-2..y+2 (w0..w4, clamped loads). y is block-uniform.
__device__ __forceinline__ void yder(float4 w0, float4 w1, float4 w2, float4 w3, float4 w4,
                                     int y, float4& d1, float4& d2) {
    if (y == 0) {
        d1 = v_sub(w3, w2);
        d2 = v_fmas(0.5f, w4, v_fmas(0.5f, w2, v_scale(-1.0f, w3)));
    } else if (y == 1) {
        d1 = v_scale(0.5f, v_sub(w3, w1));
        d2 = v_fmas(0.25f, w4, v_fmas(-0.75f, w2, v_scale(0.5f, w1)));
    } else if (y == NN - 2) {
        d1 = v_scale(0.5f, v_sub(w3, w1));
        d2 = v_fmas(0.25f, w0, v_fmas(-0.75f, w2, v_scale(0.5f, w3)));
    } else if (y == NN - 1) {
        d1 = v_sub(w2, w1);
        d2 = v_fmas(0.5f, w0, v_fmas(0.5f, w2, v_scale(-1.0f, w1)));
    } else {
        d1 = v_scale(0.5f, v_sub(w3, w1));
        d2 = v_scale(0.25f, v_add(v_sub(w4, v_scale(2.0f, w2)), w0));
    }
}

__device__ __forceinline__ void yder1(float4 p0, float4 p1, float4 p2, int y, float4& d1) {
    if (y == 0)           d1 = v_sub(p2, p1);
    else if (y == NN - 1) d1 = v_sub(p1, p0);
    else                  d1 = v_scale(0.5f, v_sub(p2, p0));
}

// One block = one image row (256 threads x float4 = 1024 px).
// Grid = (1024 rows, 8 batch) = 8192 blocks -> 32 blocks/CU pipeline depth.
// launch_bounds(256,3): cap VGPR ~170 -> 12 waves/CU (vs 252 VGPR / 8 waves in R2).
__global__ __launch_bounds__(256, 3) void physics_residual_kernel(
    const float* __restrict__ fnow, const float* __restrict__ fnext,
    double* __restrict__ part)
{
    const int tx = threadIdx.x;
    const int y  = blockIdx.x;
    const int b  = blockIdx.y;

    const size_t cb = (size_t)b * 4 * CH + (size_t)tx * 4;
    const float* Up  = fnext + cb;
    const float* Vp  = Up + CH;
    const float* Tp  = Vp + CH;
    const float* Pp  = Tp + CH;
    const float* Unp = fnow + cb;
    const float* Vnp = Unp + CH;
    const float* Tnp = Vnp + CH;

    const int loff = (tx > 0) ? -4 : 0;
    const int roff = (tx < NN / 4 - 1) ? 4 : 0;

    const size_t yc  = (size_t)y * NN;
    const size_t ym1 = (size_t)clampr(y - 1) * NN;
    const size_t ym2 = (size_t)clampr(y - 2) * NN;
    const size_t yp1 = (size_t)clampr(y + 1) * NN;
    const size_t yp2 = (size_t)clampr(y + 2) * NN;

    // ---- issue all 21 independent float4 loads up front ----
    float4 cU = ldf4(Up + yc), lU = ldf4(Up + yc + loff), rU = ldf4(Up + yc + roff);
    float4 U0 = ldf4(Up + ym2), U1 = ldf4(Up + ym1), U3 = ldf4(Up + yp1), U4 = ldf4(Up + yp2);
    float4 cV = ldf4(Vp + yc), lV = ldf4(Vp + yc + loff), rV = ldf4(Vp + yc + roff);
    float4 V0 = ldf4(Vp + ym2), V1 = ldf4(Vp + ym1), V3 = ldf4(Vp + yp1), V4 = ldf4(Vp + yp2);
    float4 cT = ldf4(Tp + yc), lT = ldf4(Tp + yc + loff), rT = ldf4(Tp + yc + roff);
    float4 T0 = ldf4(Tp + ym2), T1 = ldf4(Tp + ym1), T3 = ldf4(Tp + yp1), T4 = ldf4(Tp + yp2);
    float4 cP = ldf4(Pp + yc), lP = ldf4(Pp + yc + loff), rP = ldf4(Pp + yc + roff);
    float4 P0 = ldf4(Pp + ym1), P2 = ldf4(Pp + yp1);
    float4 cUn = ldf4(Unp + yc);
    float4 cVn = ldf4(Vnp + yc);
    float4 cTn = ldf4(Tnp + yc);

    // ---- derivatives ----
    float4 Udx, Udxx, Vdx, Vdxx, Tdx, Tdxx, Pdx;
    xder(lU, cU, rU, tx, Udx, Udxx);
    xder(lV, cV, rV, tx, Vdx, Vdxx);
    xder(lT, cT, rT, tx, Tdx, Tdxx);
    xder1(lP, cP, rP, tx, Pdx);

    float4 Udy, Udyy, Vdy, Vdyy, Tdy, Tdyy, Pdy;
    yder(U0, U1, cU, U3, U4, y, Udy, Udyy);
    yder(V0, V1, cV, V3, V4, y, Vdy, Vdyy);
    yder(T0, T1, cT, T3, T4, y, Tdy, Tdyy);
    yder1(P0, cP, P2, y, Pdy);

    // ---- residuals ----
    float4 cont = v_add(Udx, Vdy);

    // x-momentum: (u-un)*100 + u*Udx + vn*Udy + Pdx - 0.71*(Udxx+Udyy) + 7.1*u
    float4 rx = v_fmas(100.0f, v_sub(cU, cUn), Pdx);
    rx = v_fma(cU, Udx, rx);
    rx = v_fma(cVn, Udy, rx);
    rx = v_fmas(-0.71f, v_add(Udxx, Udyy), rx);
    rx = v_fmas(7.1f, cU, rx);

    // y-momentum: (v-vn)*100 + un*Vdx + v*Vdy + Pdy - 0.71*(Vdxx+Vdyy) - 710*t + 78.1*v
    float4 ry = v_fmas(100.0f, v_sub(cV, cVn), Pdy);
    ry = v_fma(cUn, Vdx, ry);
    ry = v_fma(cV, Vdy, ry);
    ry = v_fmas(-0.71f, v_add(Vdxx, Vdyy), ry);
    ry = v_fmas(-710.0f, cT, ry);
    ry = v_fmas(78.1f, cV, ry);

    // energy: (t-tn)*100 + un*Tdx + vn*Tdy - (5/3)*(Tdxx+Tdyy) - 0.1*t
    float4 rt = v_scale(100.0f, v_sub(cT, cTn));
    rt = v_fma(cUn, Tdx, rt);
    rt = v_fma(cVn, Tdy, rt);
    rt = v_fmas(-1.6666666666666667f, v_add(Tdxx, Tdyy), rt);
    rt = v_fmas(-0.1f, cT, rt);

    float4 sq = v_mul(cont, cont);
    sq = v_fma(rx, rx, sq);
    sq = v_fma(ry, ry, sq);
    sq = v_fma(rt, rt, sq);
    float acc = (sq.x + sq.y) + (sq.z + sq.w);

    // ---- block reduction -> per-block double partial ----
    double d = (double)acc;
    #pragma unroll
    for (int off = 32; off; off >>= 1) d += __shfl_down(d, off, 64);

    __shared__ double lsum[4];
    const int lane = threadIdx.x & 63;
    const int wv   = threadIdx.x >> 6;
    if (lane == 0) lsum[wv] = d;
    __syncthreads();
    if (threadIdx.x == 0) {
        part[blockIdx.y * gridDim.x + blockIdx.x] = lsum[0] + lsum[1] + lsum[2] + lsum[3];
    }
}

__global__ __launch_bounds__(1024) void final_reduce_kernel(
    const double* __restrict__ part, int n, float* __restrict__ out)
{
    double s = 0.0;
    for (int i = threadIdx.x; i < n; i += 1024) s += part[i];

    #pragma unroll
    for (int off = 32; off; off >>= 1) s += __shfl_down(s, off, 64);

    __shared__ double lsum[16];
    const int lane = threadIdx.x & 63;
    const int wv   = threadIdx.x >> 6;
    if (lane == 0) lsum[wv] = s;
    __syncthreads();
    if (threadIdx.x == 0) {
        double tot = 0.0;
        #pragma unroll
        for (int i = 0; i < 16; ++i) tot += lsum[i];
        tot *= (1e-4 / 8388608.0);   // BASE_SCALE / mean-count (same for all 4 terms)
        tot = fmin(fmax(tot, 1e-10), 1.0);
        out[0] = (float)tot;
    }
}

extern "C" void kernel_launch(void* const* d_in, const int* in_sizes, int n_in,
                              void* d_out, int out_size, void* d_ws, size_t ws_size,
                              hipStream_t stream) {
    const float* fnow  = (const float*)d_in[0];
    const float* fnext = (const float*)d_in[1];
    double* part = (double*)d_ws;          // 8192 doubles = 64 KiB scratch
    float*  out  = (float*)d_out;

    dim3 grid(NN, 8);                      // 8192 blocks, one row each
    physics_residual_kernel<<<grid, 256, 0, stream>>>(fnow, fnext, part);
    final_reduce_kernel<<<1, 1024, 0, stream>>>(part, grid.x * grid.y, out);
}

// Round 4
// 279.304 us; speedup vs baseline: 1.0125x; 1.0125x over previous
//
#include <hip/hip_runtime.h>

#define NN 1024
#define CH ((size_t)NN * (size_t)NN)

// ---- float4 elementwise helpers ----
__device__ __forceinline__ float4 v_add(float4 a, float4 b) {
    return make_float4(a.x + b.x, a.y + b.y, a.z + b.z, a.w + b.w);
}
__device__ __forceinline__ float4 v_sub(float4 a, float4 b) {
    return make_float4(a.x - b.x, a.y - b.y, a.z - b.z, a.w - b.w);
}
__device__ __forceinline__ float4 v_mul(float4 a, float4 b) {
    return make_float4(a.x * b.x, a.y * b.y, a.z * b.z, a.w * b.w);
}
__device__ __forceinline__ float4 v_fma(float4 a, float4 b, float4 c) {
    return make_float4(fmaf(a.x, b.x, c.x), fmaf(a.y, b.y, c.y),
                       fmaf(a.z, b.z, c.z), fmaf(a.w, b.w, c.w));
}
__device__ __forceinline__ float4 v_fmas(float s, float4 a, float4 c) {
    return make_float4(fmaf(s, a.x, c.x), fmaf(s, a.y, c.y),
                       fmaf(s, a.z, c.z), fmaf(s, a.w, c.w));
}
__device__ __forceinline__ float4 v_scale(float s, float4 a) {
    return make_float4(s * a.x, s * a.y, s * a.z, s * a.w);
}

__device__ __forceinline__ float4 ldf4(const float* p) { return *(const float4*)p; }

__device__ __forceinline__ int clampr(int r) { return r < 0 ? 0 : (r > NN - 1 ? NN - 1 : r); }

// x-derivatives for 4 pixels at x = 4*tx .. 4*tx+3; l/c/r = left/center/right float4.
__device__ __forceinline__ void xder(float4 l, float4 c, float4 r, int tx,
                                     float4& d1, float4& d2) {
    d1.x = 0.5f * (c.y - l.w);
    d1.y = 0.5f * (c.z - c.x);
    d1.z = 0.5f * (c.w - c.y);
    d1.w = 0.5f * (r.x - c.z);
    d2.x = 0.25f * (c.z - 2.0f * c.x + l.z);
    d2.y = 0.25f * (c.w - 2.0f * c.y + l.w);
    d2.z = 0.25f * (r.x - 2.0f * c.z + c.x);
    d2.w = 0.25f * (r.y - 2.0f * c.w + c.y);
    if (tx == 0) {                  // pixels i=0, i=1
        d1.x = c.y - c.x;
        d2.x = 0.5f * c.z - c.y + 0.5f * c.x;
        d2.y = 0.25f * c.w - 0.75f * c.y + 0.5f * c.x;
    } else if (tx == NN / 4 - 1) {  // pixels i=n-2, i=n-1
        d2.z = 0.25f * c.x - 0.75f * c.z + 0.5f * c.w;
        d1.w = c.w - c.z;
        d2.w = 0.5f * c.y - c.z + 0.5f * c.w;
    }
}

__device__ __forceinline__ void xder1(float4 l, float4 c, float4 r, int tx, float4& d1) {
    d1.x = 0.5f * (c.y - l.w);
    d1.y = 0.5f * (c.z - c.x);
    d1.z = 0.5f * (c.w - c.y);
    d1.w = 0.5f * (r.x - c.z);
    if (tx == 0)               d1.x = c.y - c.x;
    else if (tx == NN / 4 - 1) d1.w = c.w - c.z;
}

// y-derivatives from rows y-2..y+2 (w0..w4, clamped loads). y is block-uniform.
__device__ __forceinline__ void yder(float4 w0, float4 w1, float4 w2, float4 w3, float4 w4,
                                     int y, float4& d1, float4& d2) {
    if (y == 0) {
        d1 = v_sub(w3, w2);
        d2 = v_fmas(0.5f, w4, v_fmas(0.5f, w2, v_scale(-1.0f, w3)));
    } else if (y == 1) {
        d1 = v_scale(0.5f, v_sub(w3, w1));
        d2 = v_fmas(0.25f, w4, v_fmas(-0.75f, w2, v_scale(0.5f, w1)));
    } else if (y == NN - 2) {
        d1 = v_scale(0.5f, v_sub(w3, w1));
        d2 = v_fmas(0.25f, w0, v_fmas(-0.75f, w2, v_scale(0.5f, w3)));
    } else if (y == NN - 1) {
        d1 = v_sub(w2, w1);
        d2 = v_fmas(0.5f, w0, v_fmas(0.5f, w2, v_scale(-1.0f, w1)));
    } else {
        d1 = v_scale(0.5f, v_sub(w3, w1));
        d2 = v_scale(0.25f, v_add(v_sub(w4, v_scale(2.0f, w2)), w0));
    }
}

__device__ __forceinline__ void yder1(float4 p0, float4 p1, float4 p2, int y, float4& d1) {
    if (y == 0)           d1 = v_sub(p2, p1);
    else if (y == NN - 1) d1 = v_sub(p1, p0);
    else                  d1 = v_scale(0.5f, v_sub(p2, p0));
}

// One block = one image row (256 threads x float4 = 1024 px). Grid = 8192 flat.
// XCD-aware swizzle: hardware dispatches round-robin over 8 XCDs (xcd = flat & 7),
// so give XCD k a contiguous 128-row band per batch:
//   y = (flat & 7) * 128 + ((flat >> 3) & 127),  b = flat >> 10.
// Band working set = 7 planes * 128 rows * 4 KB = 3.5 MB -> fits the 4 MiB XCD L2,
// so y+-1 / y+-2 halo re-reads become L2 hits instead of HBM/L3 re-fetches.
__global__ __launch_bounds__(256) void physics_residual_kernel(
    const float* __restrict__ fnow, const float* __restrict__ fnext,
    double* __restrict__ part)
{
    const int tx   = threadIdx.x;
    const int flat = blockIdx.x;
    const int y = ((flat & 7) << 7) | ((flat >> 3) & 127);
    const int b = flat >> 10;

    const size_t cb = (size_t)b * 4 * CH + (size_t)tx * 4;
    const float* Up  = fnext + cb;
    const float* Vp  = Up + CH;
    const float* Tp  = Vp + CH;
    const float* Pp  = Tp + CH;
    const float* Unp = fnow + cb;
    const float* Vnp = Unp + CH;
    const float* Tnp = Vnp + CH;

    const int loff = (tx > 0) ? -4 : 0;
    const int roff = (tx < NN / 4 - 1) ? 4 : 0;

    const size_t yc  = (size_t)y * NN;
    const size_t ym1 = (size_t)clampr(y - 1) * NN;
    const size_t ym2 = (size_t)clampr(y - 2) * NN;
    const size_t yp1 = (size_t)clampr(y + 1) * NN;
    const size_t yp2 = (size_t)clampr(y + 2) * NN;

    // ---- issue all 21 independent float4 loads up front ----
    float4 cU = ldf4(Up + yc), lU = ldf4(Up + yc + loff), rU = ldf4(Up + yc + roff);
    float4 U0 = ldf4(Up + ym2), U1 = ldf4(Up + ym1), U3 = ldf4(Up + yp1), U4 = ldf4(Up + yp2);
    float4 cV = ldf4(Vp + yc), lV = ldf4(Vp + yc + loff), rV = ldf4(Vp + yc + roff);
    float4 V0 = ldf4(Vp + ym2), V1 = ldf4(Vp + ym1), V3 = ldf4(Vp + yp1), V4 = ldf4(Vp + yp2);
    float4 cT = ldf4(Tp + yc), lT = ldf4(Tp + yc + loff), rT = ldf4(Tp + yc + roff);
    float4 T0 = ldf4(Tp + ym2), T1 = ldf4(Tp + ym1), T3 = ldf4(Tp + yp1), T4 = ldf4(Tp + yp2);
    float4 cP = ldf4(Pp + yc), lP = ldf4(Pp + yc + loff), rP = ldf4(Pp + yc + roff);
    float4 P0 = ldf4(Pp + ym1), P2 = ldf4(Pp + yp1);
    float4 cUn = ldf4(Unp + yc);
    float4 cVn = ldf4(Vnp + yc);
    float4 cTn = ldf4(Tnp + yc);

    // ---- derivatives ----
    float4 Udx, Udxx, Vdx, Vdxx, Tdx, Tdxx, Pdx;
    xder(lU, cU, rU, tx, Udx, Udxx);
    xder(lV, cV, rV, tx, Vdx, Vdxx);
    xder(lT, cT, rT, tx, Tdx, Tdxx);
    xder1(lP, cP, rP, tx, Pdx);

    float4 Udy, Udyy, Vdy, Vdyy, Tdy, Tdyy, Pdy;
    yder(U0, U1, cU, U3, U4, y, Udy, Udyy);
    yder(V0, V1, cV, V3, V4, y, Vdy, Vdyy);
    yder(T0, T1, cT, T3, T4, y, Tdy, Tdyy);
    yder1(P0, cP, P2, y, Pdy);

    // ---- residuals ----
    float4 cont = v_add(Udx, Vdy);

    // x-momentum: (u-un)*100 + u*Udx + vn*Udy + Pdx - 0.71*(Udxx+Udyy) + 7.1*u
    float4 rx = v_fmas(100.0f, v_sub(cU, cUn), Pdx);
    rx = v_fma(cU, Udx, rx);
    rx = v_fma(cVn, Udy, rx);
    rx = v_fmas(-0.71f, v_add(Udxx, Udyy), rx);
    rx = v_fmas(7.1f, cU, rx);

    // y-momentum: (v-vn)*100 + un*Vdx + v*Vdy + Pdy - 0.71*(Vdxx+Vdyy) - 710*t + 78.1*v
    float4 ry = v_fmas(100.0f, v_sub(cV, cVn), Pdy);
    ry = v_fma(cUn, Vdx, ry);
    ry = v_fma(cV, Vdy, ry);
    ry = v_fmas(-0.71f, v_add(Vdxx, Vdyy), ry);
    ry = v_fmas(-710.0f, cT, ry);
    ry = v_fmas(78.1f, cV, ry);

    // energy: (t-tn)*100 + un*Tdx + vn*Tdy - (5/3)*(Tdxx+Tdyy) - 0.1*t
    float4 rt = v_scale(100.0f, v_sub(cT, cTn));
    rt = v_fma(cUn, Tdx, rt);
    rt = v_fma(cVn, Tdy, rt);
    rt = v_fmas(-1.6666666666666667f, v_add(Tdxx, Tdyy), rt);
    rt = v_fmas(-0.1f, cT, rt);

    float4 sq = v_mul(cont, cont);
    sq = v_fma(rx, rx, sq);
    sq = v_fma(ry, ry, sq);
    sq = v_fma(rt, rt, sq);
    float acc = (sq.x + sq.y) + (sq.z + sq.w);

    // ---- block reduction -> per-block double partial ----
    double d = (double)acc;
    #pragma unroll
    for (int off = 32; off; off >>= 1) d += __shfl_down(d, off, 64);

    __shared__ double lsum[4];
    const int lane = threadIdx.x & 63;
    const int wv   = threadIdx.x >> 6;
    if (lane == 0) lsum[wv] = d;
    __syncthreads();
    if (threadIdx.x == 0) {
        part[flat] = lsum[0] + lsum[1] + lsum[2] + lsum[3];
    }
}

__global__ __launch_bounds__(1024) void final_reduce_kernel(
    const double* __restrict__ part, int n, float* __restrict__ out)
{
    double s = 0.0;
    for (int i = threadIdx.x; i < n; i += 1024) s += part[i];

    #pragma unroll
    for (int off = 32; off; off >>= 1) s += __shfl_down(s, off, 64);

    __shared__ double lsum[16];
    const int lane = threadIdx.x & 63;
    const int wv   = threadIdx.x >> 6;
    if (lane == 0) lsum[wv] = s;
    __syncthreads();
    if (threadIdx.x == 0) {
        double tot = 0.0;
        #pragma unroll
        for (int i = 0; i < 16; ++i) tot += lsum[i];
        tot *= (1e-4 / 8388608.0);   // BASE_SCALE / mean-count (same for all 4 terms)
        tot = fmin(fmax(tot, 1e-10), 1.0);
        out[0] = (float)tot;
    }
}

extern "C" void kernel_launch(void* const* d_in, const int* in_sizes, int n_in,
                              void* d_out, int out_size, void* d_ws, size_t ws_size,
                              hipStream_t stream) {
    const float* fnow  = (const float*)d_in[0];
    const float* fnext = (const float*)d_in[1];
    double* part = (double*)d_ws;          // 8192 doubles = 64 KiB scratch
    float*  out  = (float*)d_out;

    physics_residual_kernel<<<dim3(NN * 8), 256, 0, stream>>>(fnow, fnext, part);
    final_reduce_kernel<<<1, 1024, 0, stream>>>(part, NN * 8, out);
}